// Round 4
// baseline (748.978 us; speedup 1.0000x reference)
//
#include <hip/hip_runtime.h>
#include <cstdint>
#include <cstddef>

#define HIDDEN 2048
#define NEXP 8
#define GDIM 64
#define BTOK 4096
#define NOISE_STD 0.01f

#define BM 128
#define BN 128
#define BK 32
#define NT_K (HIDDEN / BK)
#define GTOK 8

typedef unsigned short ushort_t;
typedef short bf16x8 __attribute__((ext_vector_type(8)));
typedef float f32x4 __attribute__((ext_vector_type(4)));
typedef unsigned short ushortx8 __attribute__((ext_vector_type(8)));

__device__ __forceinline__ float sigmoid_fast(float v) {
    return 1.0f / (1.0f + __expf(-v));
}

__device__ __forceinline__ ushort_t f2bf(float f) {
    union { float f; uint32_t u; } v; v.f = f;
    uint32_t r = v.u + 0x7fffu + ((v.u >> 16) & 1u);
    return (ushort_t)(r >> 16);
}

__device__ __forceinline__ float bf2f(ushort_t u) {
    union { uint32_t u; float f; } v; v.u = (uint32_t)u << 16;
    return v.f;
}

__device__ __forceinline__ void gl2lds16(const ushort_t* g, ushort_t* l) {
    __builtin_amdgcn_global_load_lds(
        (const __attribute__((address_space(1))) unsigned int*)g,
        (__attribute__((address_space(3))) unsigned int*)l, 16, 0, 0);
}

// ---------------- f32 -> bf16 elementwise (x) ----------------
__global__ __launch_bounds__(256) void convert_x_kernel(
    const float* __restrict__ in, ushort_t* __restrict__ out)
{
    const size_t i = ((size_t)blockIdx.x * 256 + threadIdx.x) * 8;
    float4 a = *(const float4*)(in + i);
    float4 b = *(const float4*)(in + i + 4);
    ushortx8 o;
    o[0] = f2bf(a.x); o[1] = f2bf(a.y); o[2] = f2bf(a.z); o[3] = f2bf(a.w);
    o[4] = f2bf(b.x); o[5] = f2bf(b.y); o[6] = f2bf(b.z); o[7] = f2bf(b.w);
    *(ushortx8*)(out + i) = o;
}

// ---------------- f32 [k][n] -> bf16 [n][k] transpose-convert ----------------
__global__ __launch_bounds__(256) void transpose_convert_kernel(
    const float* __restrict__ in, ushort_t* __restrict__ out)
{
    __shared__ float t[64][65];
    const size_t moff = (size_t)blockIdx.z * HIDDEN * HIDDEN;
    const int r0 = blockIdx.y * 64, c0 = blockIdx.x * 64;
    const int tid = threadIdx.x;
    const int tr = tid >> 4, tc = (tid & 15) * 4;
    #pragma unroll
    for (int ii = 0; ii < 4; ++ii) {
        float4 v = *(const float4*)(in + moff + (size_t)(r0 + tr + ii * 16) * HIDDEN + c0 + tc);
        t[tr + ii * 16][tc + 0] = v.x; t[tr + ii * 16][tc + 1] = v.y;
        t[tr + ii * 16][tc + 2] = v.z; t[tr + ii * 16][tc + 3] = v.w;
    }
    __syncthreads();
    const int orow = tid >> 3;
    const int ok = (tid & 7) * 8;
    #pragma unroll
    for (int jj = 0; jj < 2; ++jj) {
        const int c = orow + jj * 32;
        ushortx8 o;
        #pragma unroll
        for (int e = 0; e < 8; ++e) o[e] = f2bf(t[ok + e][c]);
        *(ushortx8*)(out + moff + (size_t)(c0 + c) * HIDDEN + r0 + ok) = o;
    }
}

// ---------------- Gating: 8 tokens/block; writes slot lists + token->slot map ----------------
__global__ __launch_bounds__(256) void gating_kernel(
    const float* __restrict__ x, const float* __restrict__ noise,
    const float* __restrict__ gw1, const float* __restrict__ gb1,
    const float* __restrict__ gw2, const float* __restrict__ gb2,
    float* __restrict__ gating_out, int* __restrict__ tlist,
    int* __restrict__ counts, int4* __restrict__ tok2i,
    float2* __restrict__ tok2w)
{
    const int tid = threadIdx.x;
    const int t0 = blockIdx.x * GTOK;

    __shared__ float xs[GTOK][64];
    __shared__ float hs[GTOK][GDIM + 1];
    __shared__ float logit_s[GTOK][NEXP];

    const int tok = tid >> 5;
    const int jj = (tid & 31) * 2;
    float accx = 0.f, accy = 0.f;

    for (int kc = 0; kc < HIDDEN / 64; ++kc) {
        const int k0 = kc * 64;
        __syncthreads();
        if (tid < 128) {
            const int r = tid >> 4, c4 = (tid & 15) * 4;
            *(float4*)&xs[r][c4] = *(const float4*)(x + (size_t)(t0 + r) * HIDDEN + k0 + c4);
        }
        __syncthreads();
        #pragma unroll 8
        for (int kk = 0; kk < 64; ++kk) {
            const float xv = xs[tok][kk];
            const float2 g = *(const float2*)(gw1 + (size_t)(k0 + kk) * GDIM + jj);
            accx = fmaf(xv, g.x, accx);
            accy = fmaf(xv, g.y, accy);
        }
    }
    hs[tok][jj]     = fmaxf(accx + gb1[jj], 0.f);
    hs[tok][jj + 1] = fmaxf(accy + gb1[jj + 1], 0.f);
    __syncthreads();

    if (tid < GTOK * NEXP) {
        const int t = tid >> 3, e = tid & 7;
        float l = gb2[e];
        #pragma unroll
        for (int j2 = 0; j2 < GDIM; ++j2)
            l = fmaf(hs[t][j2], gw2[j2 * NEXP + e], l);
        logit_s[t][e] = l;
    }
    __syncthreads();

    if (tid < GTOK) {
        const int token = t0 + tid;
        float g[NEXP];
        float m = logit_s[tid][0];
        #pragma unroll
        for (int e = 1; e < NEXP; ++e) m = fmaxf(m, logit_s[tid][e]);
        float se = 0.f;
        #pragma unroll
        for (int e = 0; e < NEXP; ++e) { g[e] = expf(logit_s[tid][e] - m); se += g[e]; }
        float inv = 1.0f / se;
        #pragma unroll
        for (int e = 0; e < NEXP; ++e) {
            g[e] = g[e] * inv + noise[(size_t)token * NEXP + e] * NOISE_STD;
            gating_out[(size_t)token * NEXP + e] = g[e];
        }
        int i1 = 0;
        #pragma unroll
        for (int e = 1; e < NEXP; ++e) if (g[e] > g[i1]) i1 = e;
        int i2 = (i1 == 0) ? 1 : 0;
        #pragma unroll
        for (int e = 0; e < NEXP; ++e) if (e != i1 && g[e] > g[i2]) i2 = e;
        float wsum = g[i1] + g[i2];
        int p1 = atomicAdd(&counts[i1], 1);
        tlist[i1 * BTOK + p1] = token;
        int p2 = atomicAdd(&counts[i2], 1);
        tlist[i2 * BTOK + p2] = token;
        tok2i[token] = make_int4(i1, p1, i2, p2);
        tok2w[token] = make_float2(g[i1] / wsum, g[i2] / wsum);
    }
}

// ---------------- Balancing loss + expert row-offset prefix ----------------
__global__ __launch_bounds__(256) void loss_kernel(
    const float* __restrict__ gating, const int* __restrict__ counts,
    int* __restrict__ offs, float* __restrict__ out_loss)
{
    __shared__ float red[256][NEXP];
    const int tid = threadIdx.x;
    float loc[NEXP];
    #pragma unroll
    for (int e = 0; e < NEXP; ++e) loc[e] = 0.f;
    for (int t = tid; t < BTOK; t += 256) {
        #pragma unroll
        for (int e = 0; e < NEXP; ++e) loc[e] += gating[(size_t)t * NEXP + e];
    }
    #pragma unroll
    for (int e = 0; e < NEXP; ++e) red[tid][e] = loc[e];
    __syncthreads();
    for (int s = 128; s > 0; s >>= 1) {
        if (tid < s) {
            #pragma unroll
            for (int e = 0; e < NEXP; ++e) red[tid][e] += red[tid + s][e];
        }
        __syncthreads();
    }
    if (tid == 0) {
        float loss = 0.f;
        #pragma unroll
        for (int e = 0; e < NEXP; ++e) {
            float p = red[0][e] / (float)BTOK;
            float d = 0.125f - p;
            loss += d * d;
        }
        out_loss[0] = (loss / 8.0f) * 0.01f;
        int o = 0;
        #pragma unroll
        for (int e = 0; e < NEXP; ++e) { offs[e] = o; o += counts[e]; }
        offs[NEXP] = o;
    }
}

// ---------------- Gathered expert MFMA GEMM -> dense eout (no atomics) ----------------
__global__ __launch_bounds__(256) void expert_kernel(
    const ushort_t* __restrict__ xb, const ushort_t* __restrict__ ewT,
    const float* __restrict__ eb, const int* __restrict__ counts,
    const int* __restrict__ offs, const int* __restrict__ tlist,
    ushort_t* __restrict__ eout)
{
    // bijective chunked XCD swizzle: XCD k owns expert k's full grid;
    // within a chunk n0 is outer, m0 inner -> A rows L2-resident per XCD.
    const int orig = blockIdx.x;
    const int wgid = (orig & 7) * 512 + (orig >> 3);
    const int e = wgid >> 9;
    const int rem = wgid & 511;
    const int n0 = (rem >> 5) * BN;
    const int m0 = (rem & 31) * BM;

    const int cnt = counts[e];
    if (m0 >= cnt) return;
    const ushort_t* __restrict__ wT = ewT + (size_t)e * HIDDEN * HIDDEN;

    __shared__ int rows_s[BM];
    __shared__ ushort_t sA[2][BM * BK];
    __shared__ ushort_t sB[2][BN * BK];

    const int tid = threadIdx.x;
    if (tid < BM) {
        int mi = m0 + tid;
        rows_s[tid] = (mi < cnt) ? tlist[e * BTOK + mi] : -1;
    }
    __syncthreads();

    const int lane = tid & 63;
    const int wid = tid >> 6;
    const int wr = (wid >> 1) * 64;
    const int wc = (wid & 1) * 64;
    const int lr = lane & 15;
    const int sg = (lane >> 4) ^ ((lane >> 1) & 3);

    const int crow = wid * 32 + (lane >> 2);
    const int kgr = (((lane & 3) ^ ((lane >> 3) & 3)) << 3);
    const int tokA0 = max(rows_s[crow], 0);
    const int tokA1 = max(rows_s[crow + 16], 0);
    const ushort_t* srcA0 = xb + (size_t)tokA0 * HIDDEN + kgr;
    const ushort_t* srcA1 = xb + (size_t)tokA1 * HIDDEN + kgr;
    const ushort_t* srcB0 = wT + (size_t)(n0 + crow) * HIDDEN + kgr;
    const ushort_t* srcB1 = wT + (size_t)(n0 + crow + 16) * HIDDEN + kgr;

    f32x4 acc[4][4];
    #pragma unroll
    for (int m = 0; m < 4; ++m)
        #pragma unroll
        for (int n = 0; n < 4; ++n) acc[m][n] = (f32x4){0.f, 0.f, 0.f, 0.f};

    gl2lds16(srcA0, &sA[0][(wid * 32) * BK]);
    gl2lds16(srcA1, &sA[0][(wid * 32 + 16) * BK]);
    gl2lds16(srcB0, &sB[0][(wid * 32) * BK]);
    gl2lds16(srcB1, &sB[0][(wid * 32 + 16) * BK]);
    __syncthreads();

    int cur = 0;
    for (int kt = 0; kt < NT_K; ++kt) {
        if (kt + 1 < NT_K) {
            const int k0 = (kt + 1) * BK;
            gl2lds16(srcA0 + k0, &sA[cur ^ 1][(wid * 32) * BK]);
            gl2lds16(srcA1 + k0, &sA[cur ^ 1][(wid * 32 + 16) * BK]);
            gl2lds16(srcB0 + k0, &sB[cur ^ 1][(wid * 32) * BK]);
            gl2lds16(srcB1 + k0, &sB[cur ^ 1][(wid * 32 + 16) * BK]);
        }
        const ushort_t* Ab = sA[cur];
        const ushort_t* Bb = sB[cur];
        bf16x8 af[4], bfr[4];
        #pragma unroll
        for (int m = 0; m < 4; ++m)
            af[m] = *(const bf16x8*)&Ab[(wr + m * 16 + lr) * BK + sg * 8];
        #pragma unroll
        for (int n = 0; n < 4; ++n)
            bfr[n] = *(const bf16x8*)&Bb[(wc + n * 16 + lr) * BK + sg * 8];
        #pragma unroll
        for (int m = 0; m < 4; ++m)
            #pragma unroll
            for (int n = 0; n < 4; ++n)
                acc[m][n] = __builtin_amdgcn_mfma_f32_16x16x32_bf16(af[m], bfr[n], acc[m][n], 0, 0, 0);
        __syncthreads();
        cur ^= 1;
    }

    // epilogue: dense coalesced stores into eout rows [offs[e]+m0, ...)
    const int grow0 = offs[e] + m0;
    float bvn[4];
    #pragma unroll
    for (int n = 0; n < 4; ++n)
        bvn[n] = eb[(size_t)e * HIDDEN + n0 + wc + n * 16 + lr];
    #pragma unroll
    for (int m = 0; m < 4; ++m) {
        #pragma unroll
        for (int q = 0; q < 4; ++q) {
            const int lrow = wr + m * 16 + (lane >> 4) * 4 + q;
            if (rows_s[lrow] < 0) continue;
            ushort_t* dst = eout + (size_t)(grow0 + lrow) * HIDDEN + n0 + wc + lr;
            #pragma unroll
            for (int n = 0; n < 4; ++n)
                dst[n * 16] = f2bf(sigmoid_fast(acc[m][n][q] + bvn[n]));
        }
    }
}

// ---------------- Shared MFMA GEMM + gather-combine ----------------
__global__ __launch_bounds__(256) void shared_final_kernel(
    const ushort_t* __restrict__ xb, const ushort_t* __restrict__ swT,
    const float* __restrict__ x, const float* __restrict__ bias,
    const float* __restrict__ sscale, const float* __restrict__ rscale,
    const ushort_t* __restrict__ eout, const int4* __restrict__ tok2i,
    const float2* __restrict__ tok2w, const int* __restrict__ offs,
    float* __restrict__ out)
{
    const int orig = blockIdx.x;
    const int wgid = (orig & 7) * 64 + (orig >> 3);
    const int n0 = (wgid >> 5) * BN;
    const int m0 = (wgid & 31) * BM;

    __shared__ ushort_t sA[2][BM * BK];
    __shared__ ushort_t sB[2][BN * BK];

    const int tid = threadIdx.x;
    const int lane = tid & 63;
    const int wid = tid >> 6;
    const int wr = (wid >> 1) * 64;
    const int wc = (wid & 1) * 64;
    const int lr = lane & 15;
    const int sg = (lane >> 4) ^ ((lane >> 1) & 3);

    const int crow = wid * 32 + (lane >> 2);
    const int kgr = (((lane & 3) ^ ((lane >> 3) & 3)) << 3);
    const ushort_t* srcA0 = xb + (size_t)(m0 + crow) * HIDDEN + kgr;
    const ushort_t* srcA1 = xb + (size_t)(m0 + crow + 16) * HIDDEN + kgr;
    const ushort_t* srcB0 = swT + (size_t)(n0 + crow) * HIDDEN + kgr;
    const ushort_t* srcB1 = swT + (size_t)(n0 + crow + 16) * HIDDEN + kgr;

    f32x4 acc[4][4];
    #pragma unroll
    for (int m = 0; m < 4; ++m)
        #pragma unroll
        for (int n = 0; n < 4; ++n) acc[m][n] = (f32x4){0.f, 0.f, 0.f, 0.f};

    gl2lds16(srcA0, &sA[0][(wid * 32) * BK]);
    gl2lds16(srcA1, &sA[0][(wid * 32 + 16) * BK]);
    gl2lds16(srcB0, &sB[0][(wid * 32) * BK]);
    gl2lds16(srcB1, &sB[0][(wid * 32 + 16) * BK]);
    __syncthreads();

    int cur = 0;
    for (int kt = 0; kt < NT_K; ++kt) {
        if (kt + 1 < NT_K) {
            const int k0 = (kt + 1) * BK;
            gl2lds16(srcA0 + k0, &sA[cur ^ 1][(wid * 32) * BK]);
            gl2lds16(srcA1 + k0, &sA[cur ^ 1][(wid * 32 + 16) * BK]);
            gl2lds16(srcB0 + k0, &sB[cur ^ 1][(wid * 32) * BK]);
            gl2lds16(srcB1 + k0, &sB[cur ^ 1][(wid * 32 + 16) * BK]);
        }
        const ushort_t* Ab = sA[cur];
        const ushort_t* Bb = sB[cur];
        bf16x8 af[4], bfr[4];
        #pragma unroll
        for (int m = 0; m < 4; ++m)
            af[m] = *(const bf16x8*)&Ab[(wr + m * 16 + lr) * BK + sg * 8];
        #pragma unroll
        for (int n = 0; n < 4; ++n)
            bfr[n] = *(const bf16x8*)&Bb[(wc + n * 16 + lr) * BK + sg * 8];
        #pragma unroll
        for (int m = 0; m < 4; ++m)
            #pragma unroll
            for (int n = 0; n < 4; ++n)
                acc[m][n] = __builtin_amdgcn_mfma_f32_16x16x32_bf16(af[m], bfr[n], acc[m][n], 0, 0, 0);
        __syncthreads();
        cur ^= 1;
    }

    const float ss = *sscale;
    const float rs = *rscale;
    float bvn[4];
    #pragma unroll
    for (int n = 0; n < 4; ++n)
        bvn[n] = bias[n0 + wc + n * 16 + lr];
    const int cb = n0 + wc + lr;
    #pragma unroll
    for (int m = 0; m < 4; ++m) {
        #pragma unroll
        for (int q = 0; q < 4; ++q) {
            const int row = m0 + wr + m * 16 + (lane >> 4) * 4 + q;
            const int4 t2 = tok2i[row];
            const float2 tw = tok2w[row];
            const size_t g1 = (size_t)(offs[t2.x] + t2.y) * HIDDEN + cb;
            const size_t g2 = (size_t)(offs[t2.z] + t2.w) * HIDDEN + cb;
            const size_t base = (size_t)row * HIDDEN + cb;
            #pragma unroll
            for (int n = 0; n < 4; ++n) {
                const float xv = x[base + n * 16];
                const float rv = tw.x * bf2f(eout[g1 + n * 16]) + tw.y * bf2f(eout[g2 + n * 16]);
                out[base + n * 16] = xv + ss * sigmoid_fast(acc[m][n][q] + bvn[n]) + rs * (xv + rv);
            }
        }
    }
}

extern "C" void kernel_launch(void* const* d_in, const int* in_sizes, int n_in,
                              void* d_out, int out_size, void* d_ws, size_t ws_size,
                              hipStream_t stream) {
    const float* x      = (const float*)d_in[0];
    const float* noise  = (const float*)d_in[1];
    const float* gw1    = (const float*)d_in[2];
    const float* gb1    = (const float*)d_in[3];
    const float* gw2    = (const float*)d_in[4];
    const float* gb2    = (const float*)d_in[5];
    const float* sw     = (const float*)d_in[6];
    const float* sb     = (const float*)d_in[7];
    const float* sscale = (const float*)d_in[8];
    const float* ew     = (const float*)d_in[9];
    const float* ebias  = (const float*)d_in[10];
    const float* rscale = (const float*)d_in[11];
    float* out = (float*)d_out;

    // workspace layout (byte offsets, all 16B-aligned)
    char* wsb = (char*)d_ws;
    ushort_t* eout  = (ushort_t*)wsb;                       // 2*BTOK rows * H bf16 = 33,554,432 B
    char* p = wsb + (size_t)2 * BTOK * HIDDEN * sizeof(ushort_t);
    int* counts = (int*)p;            p += 32;              // 8 ints (+pad)
    int* offs   = (int*)p;            p += 64;              // 9 ints (+pad)
    float* gating = (float*)p;        p += (size_t)BTOK * NEXP * 4;   // 131072 B
    int* tlist  = (int*)p;            p += (size_t)NEXP * BTOK * 4;   // 131072 B
    int4* tok2i = (int4*)p;           p += (size_t)BTOK * 16;         // 65536 B
    float2* tok2w = (float2*)p;       p += (size_t)BTOK * 8;          // 32768 B
    ushort_t* xb  = (ushort_t*)p;     p += (size_t)BTOK * HIDDEN * 2; // 16,777,216 B
    ushort_t* ewT = (ushort_t*)p;     p += (size_t)NEXP * HIDDEN * HIDDEN * 2; // 67,108,864 B
    ushort_t* swT = (ushort_t*)p;                                     // 8,388,608 B

    hipMemsetAsync(counts, 0, 32, stream);

    convert_x_kernel<<<(BTOK * HIDDEN) / (256 * 8), 256, 0, stream>>>(x, xb);
    transpose_convert_kernel<<<dim3(HIDDEN / 64, HIDDEN / 64, NEXP), 256, 0, stream>>>(ew, ewT);
    transpose_convert_kernel<<<dim3(HIDDEN / 64, HIDDEN / 64, 1), 256, 0, stream>>>(sw, swT);

    gating_kernel<<<BTOK / GTOK, 256, 0, stream>>>(x, noise, gw1, gb1, gw2, gb2,
                                                   gating, tlist, counts, tok2i, tok2w);
    loss_kernel<<<1, 256, 0, stream>>>(gating, counts, offs, out + (size_t)BTOK * HIDDEN);

    expert_kernel<<<16 * 32 * NEXP, 256, 0, stream>>>(
        xb, ewT, ebias, counts, offs, tlist, eout);
    shared_final_kernel<<<16 * 32, 256, 0, stream>>>(
        xb, swT, x, sb, sscale, rscale, eout, tok2i, tok2w, offs, out);
}